// Round 2
// baseline (627.868 us; speedup 1.0000x reference)
//
#include <hip/hip_runtime.h>
#include <math.h>

#define N_NODES 100000
#define F_IN    100
#define HIDDEN  16
#define N_CLASS 18
#define SCAN_NB ((N_NODES + 255) / 256)   // 391 blocks of 256

// ---- edge dtype detector: int64 little-endian (values < 2^31) has all-zero odd int32 words
__global__ void k_detect(const int* __restrict__ ei, int* __restrict__ flag) {
    int z = 1;
    for (int i = 0; i < 16; ++i) {
        if (ei[2 * i + 1] != 0) z = 0;
    }
    *flag = z;  // 1 => int64 layout, 0 => int32 layout
}

__device__ __forceinline__ int edge_at(const int* __restrict__ ei, long long idx, int is64) {
    return is64 ? ei[2 * idx] : ei[idx];
}

// ---- histogram of dst: cnt[d]++
__global__ __launch_bounds__(256) void k_hist(const int* __restrict__ ei, long long E,
                                              const int* __restrict__ flag,
                                              int* __restrict__ cnt) {
    long long e = (long long)blockIdx.x * 256 + threadIdx.x;
    if (e >= E) return;
    int is64 = *flag;
    int d = edge_at(ei, E + e, is64);
    atomicAdd(&cnt[d], 1);
}

// ---- dinv = rsqrt(cnt + 1)   (+1 = self-loop)
__global__ __launch_bounds__(256) void k_dinv(const int* __restrict__ cnt,
                                              float* __restrict__ dinv) {
    int i = blockIdx.x * 256 + threadIdx.x;
    if (i < N_NODES) dinv[i] = rsqrtf((float)cnt[i] + 1.0f);
}

// ---- 3-kernel exclusive scan over cnt -> row_start (and cursor copy)
__global__ __launch_bounds__(256) void k_scan1(const int* __restrict__ cnt,
                                               int* __restrict__ incl,
                                               int* __restrict__ bsum) {
    __shared__ int s[256];
    int tid = threadIdx.x;
    int i = blockIdx.x * 256 + tid;
    int v = (i < N_NODES) ? cnt[i] : 0;
    s[tid] = v;
    __syncthreads();
    for (int off = 1; off < 256; off <<= 1) {
        int t = (tid >= off) ? s[tid - off] : 0;
        __syncthreads();
        s[tid] += t;
        __syncthreads();
    }
    if (i < N_NODES) incl[i] = s[tid];
    if (tid == 255) bsum[blockIdx.x] = s[255];
}

__global__ __launch_bounds__(512) void k_scan2(int* __restrict__ bsum) {
    __shared__ int s[512];
    int tid = threadIdx.x;
    int v = (tid < SCAN_NB) ? bsum[tid] : 0;
    s[tid] = v;
    __syncthreads();
    for (int off = 1; off < 512; off <<= 1) {
        int t = (tid >= off) ? s[tid - off] : 0;
        __syncthreads();
        s[tid] += t;
        __syncthreads();
    }
    if (tid < SCAN_NB) bsum[tid] = s[tid];  // inclusive
}

__global__ __launch_bounds__(256) void k_scan3(const int* __restrict__ cnt,
                                               const int* __restrict__ incl,
                                               const int* __restrict__ bsum,
                                               long long E,
                                               int* __restrict__ row_start,
                                               int* __restrict__ cursor) {
    int i = blockIdx.x * 256 + threadIdx.x;
    if (i >= N_NODES) return;
    int b = i >> 8;
    int base = (b > 0) ? bsum[b - 1] : 0;
    int rs = base + incl[i] - cnt[i];   // exclusive
    row_start[i] = rs;
    cursor[i] = rs;
    if (i == 0) row_start[N_NODES] = (int)E;
}

// ---- fill CSR: srcs[pos] = src for each edge, binned by dst
__global__ __launch_bounds__(256) void k_fill(const int* __restrict__ ei, long long E,
                                              const int* __restrict__ flag,
                                              int* __restrict__ cursor,
                                              int* __restrict__ srcs) {
    long long e = (long long)blockIdx.x * 256 + threadIdx.x;
    if (e >= E) return;
    int is64 = *flag;
    int s = edge_at(ei, e, is64);
    int d = edge_at(ei, E + e, is64);
    int pos = atomicAdd(&cursor[d], 1);
    srcs[pos] = s;
}

// ---- h = relu(x @ W1 + b1)   [N,100]@[100,16]
__global__ __launch_bounds__(256) void k_lin1(const float* __restrict__ x,
                                              const float* __restrict__ W1,
                                              const float* __restrict__ b1,
                                              float* __restrict__ h) {
    __shared__ float sW[F_IN * HIDDEN];
    __shared__ float sb[HIDDEN];
    for (int i = threadIdx.x; i < F_IN * HIDDEN; i += 256) sW[i] = W1[i];
    if (threadIdx.x < HIDDEN) sb[threadIdx.x] = b1[threadIdx.x];
    __syncthreads();
    int node = blockIdx.x * 256 + threadIdx.x;
    if (node >= N_NODES) return;

    float acc[HIDDEN];
#pragma unroll
    for (int j = 0; j < HIDDEN; ++j) acc[j] = sb[j];

    const float4* x4 = reinterpret_cast<const float4*>(x + (long long)node * F_IN);
#pragma unroll 2
    for (int k4 = 0; k4 < F_IN / 4; ++k4) {
        float4 xv = x4[k4];
        const float* w = &sW[k4 * 4 * HIDDEN];
#pragma unroll
        for (int j = 0; j < HIDDEN; ++j) {
            acc[j] += xv.x * w[0 * HIDDEN + j];
            acc[j] += xv.y * w[1 * HIDDEN + j];
            acc[j] += xv.z * w[2 * HIDDEN + j];
            acc[j] += xv.w * w[3 * HIDDEN + j];
        }
    }
    float4* hr = reinterpret_cast<float4*>(h + (long long)node * HIDDEN);
#pragma unroll
    for (int q = 0; q < HIDDEN / 4; ++q) {
        float4 o;
        o.x = fmaxf(acc[q * 4 + 0], 0.0f);
        o.y = fmaxf(acc[q * 4 + 1], 0.0f);
        o.z = fmaxf(acc[q * 4 + 2], 0.0f);
        o.w = fmaxf(acc[q * 4 + 3], 0.0f);
        hr[q] = o;
    }
}

// ---- tmp' = dinv[i] * (h @ W)
__global__ __launch_bounds__(256) void k_mm16(const float* __restrict__ h,
                                              const float* __restrict__ W,
                                              const float* __restrict__ dinv,
                                              float* __restrict__ tmpp) {
    __shared__ float sW[HIDDEN * HIDDEN];
    if (threadIdx.x < HIDDEN * HIDDEN) sW[threadIdx.x] = W[threadIdx.x];
    __syncthreads();
    int node = blockIdx.x * 256 + threadIdx.x;
    if (node >= N_NODES) return;

    float hv[HIDDEN];
    const float4* hr = reinterpret_cast<const float4*>(h + (long long)node * HIDDEN);
#pragma unroll
    for (int q = 0; q < HIDDEN / 4; ++q) {
        float4 v = hr[q];
        hv[q * 4 + 0] = v.x; hv[q * 4 + 1] = v.y;
        hv[q * 4 + 2] = v.z; hv[q * 4 + 3] = v.w;
    }
    float di = dinv[node];
    float out[HIDDEN];
#pragma unroll
    for (int j = 0; j < HIDDEN; ++j) out[j] = 0.0f;
#pragma unroll
    for (int k = 0; k < HIDDEN; ++k) {
        float hk = hv[k];
#pragma unroll
        for (int j = 0; j < HIDDEN; ++j) out[j] += hk * sW[k * HIDDEN + j];
    }
    float4* tp = reinterpret_cast<float4*>(tmpp + (long long)node * HIDDEN);
#pragma unroll
    for (int q = 0; q < HIDDEN / 4; ++q) {
        float4 o;
        o.x = di * out[q * 4 + 0];
        o.y = di * out[q * 4 + 1];
        o.z = di * out[q * 4 + 2];
        o.w = di * out[q * 4 + 3];
        tp[q] = o;
    }
}

// ---- pull aggregation, fused epilogue: h[n] = relu(dinv[n]*(sum_src tmpp[src] + tmpp[n]) + b)
// one wave per node: lane = f + 16*chunk; chunk strides the CSR range by 4
__global__ __launch_bounds__(256) void k_aggr(const int* __restrict__ row_start,
                                              const int* __restrict__ srcs,
                                              const float* __restrict__ tmpp,
                                              const float* __restrict__ dinv,
                                              const float* __restrict__ b,
                                              float* __restrict__ h) {
    int wave = (blockIdx.x * 256 + threadIdx.x) >> 6;
    int lane = threadIdx.x & 63;
    if (wave >= N_NODES) return;
    int n = wave;
    int f = lane & 15;
    int c = lane >> 4;
    int s0 = row_start[n], s1 = row_start[n + 1];
    float acc = 0.0f;
    for (int i = s0 + c; i < s1; i += 4) {
        int s = srcs[i];
        acc += tmpp[(long long)s * HIDDEN + f];
    }
    // reduce across the 4 chunks (lanes xor 16, 32)
    acc += __shfl_xor(acc, 16);
    acc += __shfl_xor(acc, 32);
    if (c == 0) {
        float v = dinv[n] * (acc + tmpp[(long long)n * HIDDEN + f]) + b[f];
        h[(long long)n * HIDDEN + f] = fmaxf(v, 0.0f);
    }
}

// ---- out = log_softmax(h @ W2 + b2)
__global__ __launch_bounds__(256) void k_out(const float* __restrict__ h,
                                             const float* __restrict__ W2,
                                             const float* __restrict__ b2,
                                             float* __restrict__ out) {
    __shared__ float sW[HIDDEN * N_CLASS];
    __shared__ float sb[N_CLASS];
    for (int i = threadIdx.x; i < HIDDEN * N_CLASS; i += 256) sW[i] = W2[i];
    if (threadIdx.x < N_CLASS) sb[threadIdx.x] = b2[threadIdx.x];
    __syncthreads();
    int node = blockIdx.x * 256 + threadIdx.x;
    if (node >= N_NODES) return;

    float hv[HIDDEN];
    const float4* hr = reinterpret_cast<const float4*>(h + (long long)node * HIDDEN);
#pragma unroll
    for (int q = 0; q < HIDDEN / 4; ++q) {
        float4 v = hr[q];
        hv[q * 4 + 0] = v.x; hv[q * 4 + 1] = v.y;
        hv[q * 4 + 2] = v.z; hv[q * 4 + 3] = v.w;
    }
    float z[N_CLASS];
#pragma unroll
    for (int c = 0; c < N_CLASS; ++c) z[c] = sb[c];
#pragma unroll
    for (int k = 0; k < HIDDEN; ++k) {
        float hk = hv[k];
#pragma unroll
        for (int c = 0; c < N_CLASS; ++c) z[c] += hk * sW[k * N_CLASS + c];
    }
    float m = z[0];
#pragma unroll
    for (int c = 1; c < N_CLASS; ++c) m = fmaxf(m, z[c]);
    float ssum = 0.0f;
#pragma unroll
    for (int c = 0; c < N_CLASS; ++c) ssum += expf(z[c] - m);
    float l = m + logf(ssum);
    float* orow = out + (long long)node * N_CLASS;
#pragma unroll
    for (int c = 0; c < N_CLASS; ++c) orow[c] = z[c] - l;
}

extern "C" void kernel_launch(void* const* d_in, const int* in_sizes, int n_in,
                              void* d_out, int out_size, void* d_ws, size_t ws_size,
                              hipStream_t stream) {
    const float* x   = (const float*)d_in[0];
    const int*   ei  = (const int*)d_in[1];
    const float* W1  = (const float*)d_in[2];
    const float* b1  = (const float*)d_in[3];
    const float* Wc0 = (const float*)d_in[4];
    const float* bc0 = (const float*)d_in[5];
    const float* Wc1 = (const float*)d_in[6];
    const float* bc1 = (const float*)d_in[7];
    const float* W2  = (const float*)d_in[8];
    const float* b2  = (const float*)d_in[9];
    float* out = (float*)d_out;

    long long E = (long long)in_sizes[1] / 2;

    char* p = (char*)d_ws;
    int* flag      = (int*)p;  p += 256;
    int* cnt       = (int*)p;  p += sizeof(int) * N_NODES;
    int* incl      = (int*)p;  p += sizeof(int) * N_NODES;
    int* bsum      = (int*)p;  p += sizeof(int) * 512;
    int* row_start = (int*)p;  p += sizeof(int) * (N_NODES + 1);
    p += 4 - (((size_t)p) & 3);  // keep 4-align (N_NODES+1 ints)
    int* cursor    = (int*)p;  p += sizeof(int) * N_NODES;
    int* srcs      = (int*)p;  p += sizeof(int) * E;
    float* dinv    = (float*)p; p += sizeof(float) * N_NODES;
    float* h       = (float*)p; p += sizeof(float) * (size_t)N_NODES * HIDDEN;
    float* tmpp    = (float*)p; p += sizeof(float) * (size_t)N_NODES * HIDDEN;

    const int nblk_node = (N_NODES + 255) / 256;
    const int nblk_edge = (int)((E + 255) / 256);
    const int nblk_aggr = (int)(((long long)N_NODES * 64 + 255) / 256);

    hipMemsetAsync(cnt, 0, sizeof(int) * N_NODES, stream);
    k_detect<<<1, 1, 0, stream>>>(ei, flag);
    k_hist<<<nblk_edge, 256, 0, stream>>>(ei, E, flag, cnt);
    k_dinv<<<nblk_node, 256, 0, stream>>>(cnt, dinv);

    k_scan1<<<SCAN_NB, 256, 0, stream>>>(cnt, incl, bsum);
    k_scan2<<<1, 512, 0, stream>>>(bsum);
    k_scan3<<<nblk_node, 256, 0, stream>>>(cnt, incl, bsum, E, row_start, cursor);
    k_fill<<<nblk_edge, 256, 0, stream>>>(ei, E, flag, cursor, srcs);

    k_lin1<<<nblk_node, 256, 0, stream>>>(x, W1, b1, h);

    // conv 1
    k_mm16<<<nblk_node, 256, 0, stream>>>(h, Wc0, dinv, tmpp);
    k_aggr<<<nblk_aggr, 256, 0, stream>>>(row_start, srcs, tmpp, dinv, bc0, h);

    // conv 2
    k_mm16<<<nblk_node, 256, 0, stream>>>(h, Wc1, dinv, tmpp);
    k_aggr<<<nblk_aggr, 256, 0, stream>>>(row_start, srcs, tmpp, dinv, bc1, h);

    k_out<<<nblk_node, 256, 0, stream>>>(h, W2, b2, out);
}